// Round 1
// baseline (158.994 us; speedup 1.0000x reference)
//
#include <hip/hip_runtime.h>

// FeatureTransformer: EmbeddingBag-sum
//   out[b, :] = sum_{a<32} W[af[b,a], :] + bias[:]
// B=8192, A=32, H=1024, fp32.
// One 256-thread block per batch row; thread t owns columns [4t, 4t+4).

#define FT_BATCH      8192
#define FT_MAX_ACTIVE 32
#define FT_HIDDEN     1024

__global__ __launch_bounds__(256) void FeatureTransformer_kernel(
    const int*   __restrict__ af,     // [B, 32]
    const float* __restrict__ w,      // [40960, 1024]
    const float* __restrict__ bias,   // [1024]
    float*       __restrict__ out)    // [B, 1024]
{
    const int row = blockIdx.x;
    const int t   = threadIdx.x;      // 0..255, float4 lane within the row

    __shared__ int s_idx[FT_MAX_ACTIVE];
    if (t < FT_MAX_ACTIVE) {
        s_idx[t] = af[row * FT_MAX_ACTIVE + t];
    }
    __syncthreads();

    // bias as float4 (uniform across blocks; L2-resident)
    float4 acc = reinterpret_cast<const float4*>(bias)[t];

    #pragma unroll
    for (int a = 0; a < FT_MAX_ACTIVE; ++a) {
        const long off = (long)s_idx[a] * FT_HIDDEN;
        const float4 v = reinterpret_cast<const float4*>(w + off)[t];
        acc.x += v.x;
        acc.y += v.y;
        acc.z += v.z;
        acc.w += v.w;
    }

    reinterpret_cast<float4*>(out + (long)row * FT_HIDDEN)[t] = acc;
}

extern "C" void kernel_launch(void* const* d_in, const int* in_sizes, int n_in,
                              void* d_out, int out_size, void* d_ws, size_t ws_size,
                              hipStream_t stream) {
    // setup_inputs() order: active_features (int32), weights (f32), biases (f32)
    const int*   af   = (const int*)  d_in[0];
    const float* w    = (const float*)d_in[1];
    const float* bias = (const float*)d_in[2];
    float*       out  = (float*)      d_out;

    dim3 grid(FT_BATCH);
    dim3 block(256);
    FeatureTransformer_kernel<<<grid, block, 0, stream>>>(af, w, bias, out);
}

// Round 2
// 155.283 us; speedup vs baseline: 1.0239x; 1.0239x over previous
//
#include <hip/hip_runtime.h>

// FeatureTransformer: EmbeddingBag-sum
//   out[b, :] = sum_{a<32} W[af[b,a], :] + bias[:]
// B=8192, A=32, H=1024, fp32.
// One 256-thread block per batch row; thread t owns float4 column t.
//
// R2 changes vs R1:
//  - indices read via block-uniform pointer (no LDS, no __syncthreads):
//    compiler emits scalar loads, all 32 row addresses available up front.
//  - gathers explicitly staged in 4 batches of 8 float4 temporaries with
//    4 independent accumulators -> ~8 loads in flight per thread (R1 had
//    VGPR=36, ~2-4 in flight, latency-bound at 3.1 TB/s).

#define FT_BATCH      8192
#define FT_MAX_ACTIVE 32
#define FT_HIDDEN     1024
#define FT_H4         (FT_HIDDEN / 4)   // 256 float4 per row

__global__ __launch_bounds__(256) void FeatureTransformer_kernel(
    const int*   __restrict__ af,     // [B, 32]
    const float* __restrict__ w,      // [40960, 1024]
    const float* __restrict__ bias,   // [1024]
    float*       __restrict__ out)    // [B, 1024]
{
    const int row = blockIdx.x;
    const int t   = threadIdx.x;      // 0..255

    // Block-uniform index pointer -> scalar loads (s_load), no LDS chain.
    const int* __restrict__ ip = af + row * FT_MAX_ACTIVE;

    const float4* __restrict__ w4 = reinterpret_cast<const float4*>(w);

    float4 acc0 = reinterpret_cast<const float4*>(bias)[t];
    float4 acc1 = make_float4(0.f, 0.f, 0.f, 0.f);
    float4 acc2 = make_float4(0.f, 0.f, 0.f, 0.f);
    float4 acc3 = make_float4(0.f, 0.f, 0.f, 0.f);

    #pragma unroll
    for (int b = 0; b < FT_MAX_ACTIVE / 8; ++b) {
        const int i0 = ip[b * 8 + 0];
        const int i1 = ip[b * 8 + 1];
        const int i2 = ip[b * 8 + 2];
        const int i3 = ip[b * 8 + 3];
        const int i4 = ip[b * 8 + 4];
        const int i5 = ip[b * 8 + 5];
        const int i6 = ip[b * 8 + 6];
        const int i7 = ip[b * 8 + 7];

        // Issue all 8 gathers before consuming any (8 float4 = 32 VGPRs in flight).
        const float4 v0 = w4[(size_t)i0 * FT_H4 + t];
        const float4 v1 = w4[(size_t)i1 * FT_H4 + t];
        const float4 v2 = w4[(size_t)i2 * FT_H4 + t];
        const float4 v3 = w4[(size_t)i3 * FT_H4 + t];
        const float4 v4 = w4[(size_t)i4 * FT_H4 + t];
        const float4 v5 = w4[(size_t)i5 * FT_H4 + t];
        const float4 v6 = w4[(size_t)i6 * FT_H4 + t];
        const float4 v7 = w4[(size_t)i7 * FT_H4 + t];

        acc0.x += v0.x; acc0.y += v0.y; acc0.z += v0.z; acc0.w += v0.w;
        acc1.x += v1.x; acc1.y += v1.y; acc1.z += v1.z; acc1.w += v1.w;
        acc2.x += v2.x; acc2.y += v2.y; acc2.z += v2.z; acc2.w += v2.w;
        acc3.x += v3.x; acc3.y += v3.y; acc3.z += v3.z; acc3.w += v3.w;
        acc0.x += v4.x; acc0.y += v4.y; acc0.z += v4.z; acc0.w += v4.w;
        acc1.x += v5.x; acc1.y += v5.y; acc1.z += v5.z; acc1.w += v5.w;
        acc2.x += v6.x; acc2.y += v6.y; acc2.z += v6.z; acc2.w += v6.w;
        acc3.x += v7.x; acc3.y += v7.y; acc3.z += v7.z; acc3.w += v7.w;
    }

    float4 r;
    r.x = (acc0.x + acc1.x) + (acc2.x + acc3.x);
    r.y = (acc0.y + acc1.y) + (acc2.y + acc3.y);
    r.z = (acc0.z + acc1.z) + (acc2.z + acc3.z);
    r.w = (acc0.w + acc1.w) + (acc2.w + acc3.w);

    reinterpret_cast<float4*>(out + (size_t)row * FT_HIDDEN)[t] = r;
}

extern "C" void kernel_launch(void* const* d_in, const int* in_sizes, int n_in,
                              void* d_out, int out_size, void* d_ws, size_t ws_size,
                              hipStream_t stream) {
    const int*   af   = (const int*)  d_in[0];
    const float* w    = (const float*)d_in[1];
    const float* bias = (const float*)d_in[2];
    float*       out  = (float*)      d_out;

    FeatureTransformer_kernel<<<dim3(FT_BATCH), dim3(256), 0, stream>>>(af, w, bias, out);
}